// Round 2
// baseline (1525.303 us; speedup 1.0000x reference)
//
#include <hip/hip_runtime.h>
#include <hip/hip_bf16.h>

// ===========================================================================
// WindowedAttention: B=8, N=4096, C=768, H=12, HD=64, W=16 -> 16 windows x 256
// I/O dtype: FLOAT32 (reference setup_inputs uses jnp.float32; round-1 NaN
// proved bf16 misread). Internal compute: bf16 MFMA, fp32 accumulate.
// Pipeline:
//   k1 qkv_gemm : xp(gathered via perm) @ qkv_w^T -> q/k/v bf16 planes
//   k2 attn     : per (b,w,h): softmax(QK^T * 0.125) V, fp32, two-pass;
//                 writes attn_buf (bf16) in ORIGINAL token order
//   k3 proj_gemm: attn_buf @ proj_w^T + b -> d_out (float32)
// ws: [0, 3*QKV_PLANE) bf16 q,k,v ; [3*QKV_PLANE, 4*QKV_PLANE) bf16 attn_buf
//     total 4*25165824*2 = 201 MB.
// ===========================================================================

using short8  = __attribute__((ext_vector_type(8))) short;
using short4v = __attribute__((ext_vector_type(4))) short;
using floatx4 = __attribute__((ext_vector_type(4))) float;

#define B_    8
#define N_    4096
#define C_    768
#define H_    12
#define HD_   64
#define NW_   256
#define SCALE_ 0.125f
#define QKV_PLANE ((size_t)25165824)   // B*16*12*256*64

__device__ __forceinline__ float bf2f(unsigned short u) {
  union { unsigned int i; float f; } c; c.i = ((unsigned int)u) << 16; return c.f;
}
__device__ __forceinline__ unsigned short f2bf(float f) {
  unsigned int u = __float_as_uint(f);
  u += 0x7fffu + ((u >> 16) & 1u);   // RNE
  return (unsigned short)(u >> 16);
}
__device__ __forceinline__ short4v f4bf(floatx4 f) {
  short4v s;
  s[0] = (short)f2bf(f[0]); s[1] = (short)f2bf(f[1]);
  s[2] = (short)f2bf(f[2]); s[3] = (short)f2bf(f[3]);
  return s;
}
// window position (w, t) -> original token index n
__device__ __forceinline__ int perm_n(int w, int t) {
  int rb = w >> 2, cb = w & 3, ri = t >> 4, ci = t & 15;
  return ((rb << 4) + ri) * 64 + (cb << 4) + ci;
}

// ---------------------------------------------------------------------------
// QKV GEMM: C[m][j] = sum_k A[m][k]*W[j][k];  M=32768, N=2304, K=768
// A rows gathered through window perm; f32 loads converted to bf16 in staging.
// 128x128 tile, BK=32, 256 thr = 4 waves, each wave 4x4 mfma_16x16x32 tiles.
// ---------------------------------------------------------------------------
__global__ __launch_bounds__(256) void qkv_gemm(
    const float* __restrict__ x,
    const float* __restrict__ w,
    unsigned short* __restrict__ qkv) {
  __shared__ short As[128 * 40];  // pad 32->40 (80B rows)
  __shared__ short Bs[128 * 40];
  const int tid  = threadIdx.x;
  const int bm   = blockIdx.x;    // 0..255
  const int bn   = blockIdx.y;    // 0..17
  const int wave = tid >> 6, lane = tid & 63;
  const int wm   = wave >> 1, wn = wave & 1;
  const int l15  = lane & 15, quad = lane >> 4;

  // staging: thread t loads cols [colf, colf+4) of rows rbase+32*i, i=0..3
  const int colf  = (tid & 7) << 2;   // 0..28
  const int rbase = tid >> 3;         // 0..31

  size_t aoff[4], boff[4];
#pragma unroll
  for (int i = 0; i < 4; i++) {
    int r = rbase + 32 * i;
    int mg = bm * 128 + r;
    int b = mg >> 12, p = mg & 4095;
    int n = perm_n(p >> 8, p & 255);
    aoff[i] = ((size_t)(b << 12) + (size_t)n) * C_;
    boff[i] = (size_t)(bn * 128 + r) * C_;
  }

  floatx4 acc[4][4];
#pragma unroll
  for (int i = 0; i < 4; i++)
#pragma unroll
    for (int j = 0; j < 4; j++) acc[i][j] = {0.f, 0.f, 0.f, 0.f};

  for (int k0 = 0; k0 < C_; k0 += 32) {
#pragma unroll
    for (int i = 0; i < 4; i++) {
      int r = rbase + 32 * i;
      *(short4v*)&As[r * 40 + colf] = f4bf(*(const floatx4*)(x + aoff[i] + k0 + colf));
      *(short4v*)&Bs[r * 40 + colf] = f4bf(*(const floatx4*)(w + boff[i] + k0 + colf));
    }
    __syncthreads();
    short8 af[4], bfr[4];
#pragma unroll
    for (int mi = 0; mi < 4; mi++)
      af[mi] = *(const short8*)&As[(wm * 64 + mi * 16 + l15) * 40 + quad * 8];
#pragma unroll
    for (int ni = 0; ni < 4; ni++)
      bfr[ni] = *(const short8*)&Bs[(wn * 64 + ni * 16 + l15) * 40 + quad * 8];
#pragma unroll
    for (int mi = 0; mi < 4; mi++)
#pragma unroll
      for (int ni = 0; ni < 4; ni++)
        acc[mi][ni] = __builtin_amdgcn_mfma_f32_16x16x32_bf16(
            af[mi], bfr[ni], acc[mi][ni], 0, 0, 0);
    __syncthreads();
  }

  // epilogue: C/D layout row=(quad*4+r), col=l15  [verified m89/m91]
  const int which = (bn * 128) / 768;          // 0=q 1=k 2=v
  const int jbase = bn * 128 - which * 768;
  unsigned short* dst = qkv + (size_t)which * QKV_PLANE;
#pragma unroll
  for (int mi = 0; mi < 4; mi++) {
#pragma unroll
    for (int r = 0; r < 4; r++) {
      int mg = bm * 128 + wm * 64 + mi * 16 + quad * 4 + r;
      int b = mg >> 12, p = mg & 4095;
      int wdx = p >> 8, t = p & 255;
      size_t base = (size_t)((b * 16 + wdx) * 12) * (NW_ * HD_) + (size_t)t * HD_;
#pragma unroll
      for (int ni = 0; ni < 4; ni++) {
        int jj = jbase + wn * 64 + ni * 16 + l15;
        int h = jj >> 6, d = jj & 63;
        dst[base + (size_t)h * (NW_ * HD_) + d] = f2bf(acc[mi][ni][r]);
      }
    }
  }
}

// ---------------------------------------------------------------------------
// Attention: one block per (b,w,h) = 1536 blocks, 256 thr, thread t = query t.
// Two-pass fp32 softmax (pass1 max, pass2 exp+PV), K in LDS, V in 2 halves.
// ---------------------------------------------------------------------------
__global__ __launch_bounds__(256, 2) void attn(
    const unsigned short* __restrict__ qkv,
    unsigned short* __restrict__ attn_out) {
  const int bwh = blockIdx.x;
  const int t = threadIdx.x;
  const size_t off = (size_t)bwh * (NW_ * HD_);
  const unsigned short* qb = qkv + off;
  const unsigned short* kb = qkv + QKV_PLANE + off;
  const unsigned short* vb = qkv + 2 * QKV_PLANE + off;

  __shared__ unsigned short Ks[NW_ * HD_];  // 32 KB
  __shared__ unsigned short Vs[128 * HD_];  // 16 KB

  float q[64];
  {
    const unsigned int* qp = (const unsigned int*)(qb + t * 64);
#pragma unroll
    for (int i = 0; i < 32; i++) {
      unsigned int u = qp[i];
      q[2 * i]     = bf2f((unsigned short)(u & 0xffffu)) * SCALE_;
      q[2 * i + 1] = bf2f((unsigned short)(u >> 16)) * SCALE_;
    }
  }
#pragma unroll
  for (int i = 0; i < 8; i++)
    *(short8*)&Ks[t * 64 + i * 8] = *(const short8*)(kb + t * 64 + i * 8);
  __syncthreads();

  float mmax = -1e30f;
  for (int m = 0; m < 256; m++) {
    const unsigned int* kp = (const unsigned int*)&Ks[m * 64];
    float s = 0.f;
#pragma unroll
    for (int i = 0; i < 32; i++) {
      unsigned int u = kp[i];
      s = fmaf(q[2 * i],     bf2f((unsigned short)(u & 0xffffu)), s);
      s = fmaf(q[2 * i + 1], bf2f((unsigned short)(u >> 16)), s);
    }
    mmax = fmaxf(mmax, s);
  }

  float o[64];
#pragma unroll
  for (int i = 0; i < 64; i++) o[i] = 0.f;
  float lsum = 0.f;

  for (int half = 0; half < 2; half++) {
    __syncthreads();
    {
      int r = t >> 1, co = (t & 1) * 32;
#pragma unroll
      for (int i = 0; i < 4; i++)
        *(short8*)&Vs[r * 64 + co + i * 8] =
            *(const short8*)(vb + (half * 128 + r) * 64 + co + i * 8);
    }
    __syncthreads();
    for (int mm = 0; mm < 128; mm++) {
      const unsigned int* kp = (const unsigned int*)&Ks[(half * 128 + mm) * 64];
      float s = 0.f;
#pragma unroll
      for (int i = 0; i < 32; i++) {
        unsigned int u = kp[i];
        s = fmaf(q[2 * i],     bf2f((unsigned short)(u & 0xffffu)), s);
        s = fmaf(q[2 * i + 1], bf2f((unsigned short)(u >> 16)), s);
      }
      float p = __expf(s - mmax);
      lsum += p;
      const unsigned int* vp = (const unsigned int*)&Vs[mm * 64];
#pragma unroll
      for (int i = 0; i < 32; i++) {
        unsigned int u = vp[i];
        o[2 * i]     = fmaf(p, bf2f((unsigned short)(u & 0xffffu)), o[2 * i]);
        o[2 * i + 1] = fmaf(p, bf2f((unsigned short)(u >> 16)), o[2 * i + 1]);
      }
    }
  }

  float inv = 1.f / lsum;
  int h = bwh % 12, bw = bwh / 12;
  int b = bw >> 4, wdx = bw & 15;
  int n = perm_n(wdx, t);
  unsigned int* op = (unsigned int*)(attn_out + ((size_t)(b * N_ + n)) * C_ + h * HD_);
#pragma unroll
  for (int i = 0; i < 32; i++)
    op[i] = (unsigned int)f2bf(o[2 * i] * inv) |
            ((unsigned int)f2bf(o[2 * i + 1] * inv) << 16);
}

// ---------------------------------------------------------------------------
// Proj GEMM: out[m][j] = sum_k A[m][k]*W[j][k] + b[j];  M=32768, N=768, K=768
// A = attn_buf (bf16 internal), W/bias f32, out f32.
// ---------------------------------------------------------------------------
__global__ __launch_bounds__(256) void proj_gemm(
    const unsigned short* __restrict__ a,
    const float* __restrict__ w,
    const float* __restrict__ bias,
    float* __restrict__ out) {
  __shared__ short As[128 * 40];
  __shared__ short Bs[128 * 40];
  const int tid  = threadIdx.x;
  const int bm   = blockIdx.x;   // 0..255
  const int bn   = blockIdx.y;   // 0..5
  const int wave = tid >> 6, lane = tid & 63;
  const int wm   = wave >> 1, wn = wave & 1;
  const int l15  = lane & 15, quad = lane >> 4;

  // A staging (bf16): two 16B chunks per thread
  const int c0 = tid, c1 = tid + 256;
  const int r0 = c0 >> 2, kc0 = (c0 & 3) << 3;
  const int r1 = c1 >> 2, kc1 = (c1 & 3) << 3;
  const size_t a0 = (size_t)(bm * 128 + r0) * C_;
  const size_t a1 = (size_t)(bm * 128 + r1) * C_;
  // B staging (f32 -> bf16): four float4 chunks per thread
  const int colf  = (tid & 7) << 2;
  const int rbase = tid >> 3;
  size_t boff[4];
#pragma unroll
  for (int i = 0; i < 4; i++)
    boff[i] = (size_t)(bn * 128 + rbase + 32 * i) * C_;

  floatx4 acc[4][4];
#pragma unroll
  for (int i = 0; i < 4; i++)
#pragma unroll
    for (int j = 0; j < 4; j++) acc[i][j] = {0.f, 0.f, 0.f, 0.f};

  for (int k0 = 0; k0 < C_; k0 += 32) {
    *(short8*)&As[r0 * 40 + kc0] = *(const short8*)(a + a0 + k0 + kc0);
    *(short8*)&As[r1 * 40 + kc1] = *(const short8*)(a + a1 + k0 + kc1);
#pragma unroll
    for (int i = 0; i < 4; i++) {
      int r = rbase + 32 * i;
      *(short4v*)&Bs[r * 40 + colf] = f4bf(*(const floatx4*)(w + boff[i] + k0 + colf));
    }
    __syncthreads();
    short8 af[4], bfr[4];
#pragma unroll
    for (int mi = 0; mi < 4; mi++)
      af[mi] = *(const short8*)&As[(wm * 64 + mi * 16 + l15) * 40 + quad * 8];
#pragma unroll
    for (int ni = 0; ni < 4; ni++)
      bfr[ni] = *(const short8*)&Bs[(wn * 64 + ni * 16 + l15) * 40 + quad * 8];
#pragma unroll
    for (int mi = 0; mi < 4; mi++)
#pragma unroll
      for (int ni = 0; ni < 4; ni++)
        acc[mi][ni] = __builtin_amdgcn_mfma_f32_16x16x32_bf16(
            af[mi], bfr[ni], acc[mi][ni], 0, 0, 0);
    __syncthreads();
  }

#pragma unroll
  for (int mi = 0; mi < 4; mi++) {
#pragma unroll
    for (int r = 0; r < 4; r++) {
      int mg = bm * 128 + wm * 64 + mi * 16 + quad * 4 + r;
      size_t rowb = (size_t)mg * C_;
#pragma unroll
      for (int ni = 0; ni < 4; ni++) {
        int jj = bn * 128 + wn * 64 + ni * 16 + l15;
        out[rowb + jj] = acc[mi][ni][r] + bias[jj];
      }
    }
  }
}

extern "C" void kernel_launch(void* const* d_in, const int* in_sizes, int n_in,
                              void* d_out, int out_size, void* d_ws, size_t ws_size,
                              hipStream_t stream) {
  const float* x  = (const float*)d_in[0];
  const float* qw = (const float*)d_in[1];
  const float* pw = (const float*)d_in[2];
  const float* pb = (const float*)d_in[3];
  float* out = (float*)d_out;
  unsigned short* ws  = (unsigned short*)d_ws;
  unsigned short* qkv_buf  = ws;                      // 3 * QKV_PLANE bf16
  unsigned short* attn_buf = ws + 3 * QKV_PLANE;      // 1 * QKV_PLANE bf16

  qkv_gemm<<<dim3(256, 18), dim3(256), 0, stream>>>(x, qw, qkv_buf);
  attn<<<dim3(1536), dim3(256), 0, stream>>>(qkv_buf, attn_buf);
  proj_gemm<<<dim3(256, 6), dim3(256), 0, stream>>>(attn_buf, pw, pb, out);
}

// Round 3
// 580.806 us; speedup vs baseline: 2.6262x; 2.6262x over previous
//
#include <hip/hip_runtime.h>
#include <hip/hip_bf16.h>

// ===========================================================================
// WindowedAttention: B=8, N=4096, C=768, H=12, HD=64, W=16 -> 16 windows x 256
// I/O float32; internal bf16 MFMA, fp32 accumulate.
//   k1 qkv_gemm : xp(gathered via perm) @ qkv_w^T -> q/k/v bf16 planes
//   k2 attn_mfma: flash-style per (b,w,h); S^T via mfma(K,Q), online softmax,
//                 P->LDS (b64 row-major) -> PV via mfma(P, V^T). Writes
//                 attn_buf (bf16) in ORIGINAL token order.
//   k3 proj_gemm: attn_buf @ proj_w^T + b -> d_out (float32)
// ws: 4*QKV_PLANE bf16 = 201 MB.
// ===========================================================================

using short8  = __attribute__((ext_vector_type(8))) short;
using short4v = __attribute__((ext_vector_type(4))) short;
using floatx4 = __attribute__((ext_vector_type(4))) float;

#define B_    8
#define N_    4096
#define C_    768
#define H_    12
#define HD_   64
#define NW_   256
#define SCALE_ 0.125f
#define QKV_PLANE ((size_t)25165824)   // B*16*12*256*64

__device__ __forceinline__ float bf2f(unsigned short u) {
  union { unsigned int i; float f; } c; c.i = ((unsigned int)u) << 16; return c.f;
}
__device__ __forceinline__ unsigned short f2bf(float f) {
  unsigned int u = __float_as_uint(f);
  u += 0x7fffu + ((u >> 16) & 1u);   // RNE
  return (unsigned short)(u >> 16);
}
__device__ __forceinline__ short4v f4bf(floatx4 f) {
  short4v s;
  s[0] = (short)f2bf(f[0]); s[1] = (short)f2bf(f[1]);
  s[2] = (short)f2bf(f[2]); s[3] = (short)f2bf(f[3]);
  return s;
}
// window position (w, t) -> original token index n
__device__ __forceinline__ int perm_n(int w, int t) {
  int rb = w >> 2, cb = w & 3, ri = t >> 4, ci = t & 15;
  return ((rb << 4) + ri) * 64 + (cb << 4) + ci;
}

// ---------------------------------------------------------------------------
// QKV GEMM (unchanged from round 2): M=32768, N=2304, K=768
// ---------------------------------------------------------------------------
__global__ __launch_bounds__(256) void qkv_gemm(
    const float* __restrict__ x,
    const float* __restrict__ w,
    unsigned short* __restrict__ qkv) {
  __shared__ short As[128 * 40];
  __shared__ short Bs[128 * 40];
  const int tid  = threadIdx.x;
  const int bm   = blockIdx.x;
  const int bn   = blockIdx.y;
  const int wave = tid >> 6, lane = tid & 63;
  const int wm   = wave >> 1, wn = wave & 1;
  const int l15  = lane & 15, quad = lane >> 4;

  const int colf  = (tid & 7) << 2;
  const int rbase = tid >> 3;

  size_t aoff[4], boff[4];
#pragma unroll
  for (int i = 0; i < 4; i++) {
    int r = rbase + 32 * i;
    int mg = bm * 128 + r;
    int b = mg >> 12, p = mg & 4095;
    int n = perm_n(p >> 8, p & 255);
    aoff[i] = ((size_t)(b << 12) + (size_t)n) * C_;
    boff[i] = (size_t)(bn * 128 + r) * C_;
  }

  floatx4 acc[4][4];
#pragma unroll
  for (int i = 0; i < 4; i++)
#pragma unroll
    for (int j = 0; j < 4; j++) acc[i][j] = {0.f, 0.f, 0.f, 0.f};

  for (int k0 = 0; k0 < C_; k0 += 32) {
#pragma unroll
    for (int i = 0; i < 4; i++) {
      int r = rbase + 32 * i;
      *(short4v*)&As[r * 40 + colf] = f4bf(*(const floatx4*)(x + aoff[i] + k0 + colf));
      *(short4v*)&Bs[r * 40 + colf] = f4bf(*(const floatx4*)(w + boff[i] + k0 + colf));
    }
    __syncthreads();
    short8 af[4], bfr[4];
#pragma unroll
    for (int mi = 0; mi < 4; mi++)
      af[mi] = *(const short8*)&As[(wm * 64 + mi * 16 + l15) * 40 + quad * 8];
#pragma unroll
    for (int ni = 0; ni < 4; ni++)
      bfr[ni] = *(const short8*)&Bs[(wn * 64 + ni * 16 + l15) * 40 + quad * 8];
#pragma unroll
    for (int mi = 0; mi < 4; mi++)
#pragma unroll
      for (int ni = 0; ni < 4; ni++)
        acc[mi][ni] = __builtin_amdgcn_mfma_f32_16x16x32_bf16(
            af[mi], bfr[ni], acc[mi][ni], 0, 0, 0);
    __syncthreads();
  }

  const int which = (bn * 128) / 768;
  const int jbase = bn * 128 - which * 768;
  unsigned short* dst = qkv + (size_t)which * QKV_PLANE;
#pragma unroll
  for (int mi = 0; mi < 4; mi++) {
#pragma unroll
    for (int r = 0; r < 4; r++) {
      int mg = bm * 128 + wm * 64 + mi * 16 + quad * 4 + r;
      int b = mg >> 12, p = mg & 4095;
      int wdx = p >> 8, t = p & 255;
      size_t base = (size_t)((b * 16 + wdx) * 12) * (NW_ * HD_) + (size_t)t * HD_;
#pragma unroll
      for (int ni = 0; ni < 4; ni++) {
        int jj = jbase + wn * 64 + ni * 16 + l15;
        int h = jj >> 6, d = jj & 63;
        dst[base + (size_t)h * (NW_ * HD_) + d] = f2bf(acc[mi][ni][r]);
      }
    }
  }
}

// ---------------------------------------------------------------------------
// MFMA flash attention. 1536 blocks (one per b,w,h), 512 thr = 8 waves.
// Wave wv owns query chunks mc = wv and wv+8 (16 queries each).
// KV tiled by 64 with online softmax.
// S^T = mfma(K_frag, Q_frag): C rows=keys(quad*4+r), cols=queries(l15)
//   -> P written row-major [q][kk] with contiguous b64 stores.
// PV = mfma(P_frag, Vt_frag): C rows=queries, cols=d.
// LDS: Ks 9KB + Vt 9KB + Ps 18KB = 36KB.
// ---------------------------------------------------------------------------
__global__ __launch_bounds__(512, 2) void attn_mfma(
    const unsigned short* __restrict__ qkv,
    unsigned short* __restrict__ attn_out) {
  const int bwh = blockIdx.x;
  const int tid = threadIdx.x;
  const int wv = tid >> 6, lane = tid & 63;
  const int l15 = lane & 15, quad = lane >> 4;
  const size_t off = (size_t)bwh * (NW_ * HD_);
  const unsigned short* qb = qkv + off;
  const unsigned short* kb = qkv + QKV_PLANE + off;
  const unsigned short* vb = qkv + 2 * QKV_PLANE + off;

  __shared__ short Ks[64 * 72];       // K tile [kk][d], stride 72
  __shared__ short Vt[64 * 72];       // V^T [d][kk], stride 72
  __shared__ short Ps[8][16 * 72];    // per-wave P [q][kk], stride 72

  // Q B-fragments for this wave's two m-chunks (held across kv loop)
  short8 bq[2][2];
#pragma unroll
  for (int c = 0; c < 2; c++) {
    int mc = wv + 8 * c;
#pragma unroll
    for (int kc = 0; kc < 2; kc++)
      bq[c][kc] = *(const short8*)(qb + (mc * 16 + l15) * 64 + kc * 32 + quad * 8);
  }

  floatx4 O[2][4];
#pragma unroll
  for (int c = 0; c < 2; c++)
#pragma unroll
    for (int dt = 0; dt < 4; dt++) O[c][dt] = {0.f, 0.f, 0.f, 0.f};
  float m_run[2] = {-1e30f, -1e30f};
  float l_run[2] = {0.f, 0.f};

  const int sr = tid >> 3;            // staging row 0..63
  const int sc = (tid & 7) << 3;      // staging col 0..56

  for (int t = 0; t < 4; t++) {
    __syncthreads();   // previous iter's frag reads done before restage
    {
      short8 kk8 = *(const short8*)(kb + (t * 64 + sr) * 64 + sc);
      *(short8*)&Ks[sr * 72 + sc] = kk8;
      short8 vv8 = *(const short8*)(vb + (t * 64 + sr) * 64 + sc);
#pragma unroll
      for (int j = 0; j < 8; j++) Vt[(sc + j) * 72 + sr] = vv8[j];
    }
    __syncthreads();

#pragma unroll
    for (int c = 0; c < 2; c++) {
      // --- S^T for 64 keys x 16 queries ---
      floatx4 st[4];
#pragma unroll
      for (int nt = 0; nt < 4; nt++) {
        short8 ak0 = *(const short8*)&Ks[(nt * 16 + l15) * 72 + quad * 8];
        short8 ak1 = *(const short8*)&Ks[(nt * 16 + l15) * 72 + 32 + quad * 8];
        floatx4 z = {0.f, 0.f, 0.f, 0.f};
        z = __builtin_amdgcn_mfma_f32_16x16x32_bf16(ak0, bq[c][0], z, 0, 0, 0);
        z = __builtin_amdgcn_mfma_f32_16x16x32_bf16(ak1, bq[c][1], z, 0, 0, 0);
        st[nt] = z;
      }
      // --- online softmax ---
      float s[16];
      float cmax = -1e30f;
#pragma unroll
      for (int nt = 0; nt < 4; nt++)
#pragma unroll
        for (int r = 0; r < 4; r++) {
          float v = st[nt][r] * SCALE_;
          s[nt * 4 + r] = v;
          cmax = fmaxf(cmax, v);
        }
      cmax = fmaxf(cmax, __shfl_xor(cmax, 16));
      cmax = fmaxf(cmax, __shfl_xor(cmax, 32));
      float nm = fmaxf(m_run[c], cmax);
      float alpha = __expf(m_run[c] - nm);
      m_run[c] = nm;
      float psum = 0.f;
#pragma unroll
      for (int j = 0; j < 16; j++) {
        float p = __expf(s[j] - nm);
        s[j] = p;
        psum += p;
      }
      psum += __shfl_xor(psum, 16);
      psum += __shfl_xor(psum, 32);
      l_run[c] = l_run[c] * alpha + psum;
      // --- P -> LDS row-major (contiguous b64 per tile) ---
#pragma unroll
      for (int nt = 0; nt < 4; nt++) {
        short4v pv;
        pv[0] = (short)f2bf(s[nt * 4 + 0]);
        pv[1] = (short)f2bf(s[nt * 4 + 1]);
        pv[2] = (short)f2bf(s[nt * 4 + 2]);
        pv[3] = (short)f2bf(s[nt * 4 + 3]);
        *(short4v*)&Ps[wv][l15 * 72 + nt * 16 + quad * 4] = pv;
      }
      // --- rescale O by alpha (per ROW query via bpermute) ---
      float ar[4];
#pragma unroll
      for (int r = 0; r < 4; r++) ar[r] = __shfl(alpha, quad * 4 + r);
#pragma unroll
      for (int dt = 0; dt < 4; dt++)
#pragma unroll
        for (int r = 0; r < 4; r++) O[c][dt][r] *= ar[r];
      // --- PV ---
#pragma unroll
      for (int kc = 0; kc < 2; kc++) {
        short8 ap = *(const short8*)&Ps[wv][l15 * 72 + kc * 32 + quad * 8];
#pragma unroll
        for (int dt = 0; dt < 4; dt++) {
          short8 bv = *(const short8*)&Vt[(dt * 16 + l15) * 72 + kc * 32 + quad * 8];
          O[c][dt] = __builtin_amdgcn_mfma_f32_16x16x32_bf16(ap, bv, O[c][dt], 0, 0, 0);
        }
      }
    }
  }

  // --- epilogue: normalize, write original token order ---
  int h = bwh % 12, bw = bwh / 12;
  int b = bw >> 4, wdx = bw & 15;
#pragma unroll
  for (int c = 0; c < 2; c++) {
    float linv = 1.f / l_run[c];
    float lr[4];
#pragma unroll
    for (int r = 0; r < 4; r++) lr[r] = __shfl(linv, quad * 4 + r);
    int mc = wv + 8 * c;
#pragma unroll
    for (int r = 0; r < 4; r++) {
      int q = mc * 16 + quad * 4 + r;
      int n = perm_n(wdx, q);
      unsigned short* op = attn_out + ((size_t)(b * N_ + n)) * C_ + h * HD_;
#pragma unroll
      for (int dt = 0; dt < 4; dt++)
        op[dt * 16 + l15] = f2bf(O[c][dt][r] * lr[r]);
    }
  }
}

// ---------------------------------------------------------------------------
// Proj GEMM (unchanged from round 2): M=32768, N=768, K=768
// ---------------------------------------------------------------------------
__global__ __launch_bounds__(256) void proj_gemm(
    const unsigned short* __restrict__ a,
    const float* __restrict__ w,
    const float* __restrict__ bias,
    float* __restrict__ out) {
  __shared__ short As[128 * 40];
  __shared__ short Bs[128 * 40];
  const int tid  = threadIdx.x;
  const int bm   = blockIdx.x;
  const int bn   = blockIdx.y;
  const int wave = tid >> 6, lane = tid & 63;
  const int wm   = wave >> 1, wn = wave & 1;
  const int l15  = lane & 15, quad = lane >> 4;

  const int c0 = tid, c1 = tid + 256;
  const int r0 = c0 >> 2, kc0 = (c0 & 3) << 3;
  const int r1 = c1 >> 2, kc1 = (c1 & 3) << 3;
  const size_t a0 = (size_t)(bm * 128 + r0) * C_;
  const size_t a1 = (size_t)(bm * 128 + r1) * C_;
  const int colf  = (tid & 7) << 2;
  const int rbase = tid >> 3;
  size_t boff[4];
#pragma unroll
  for (int i = 0; i < 4; i++)
    boff[i] = (size_t)(bn * 128 + rbase + 32 * i) * C_;

  floatx4 acc[4][4];
#pragma unroll
  for (int i = 0; i < 4; i++)
#pragma unroll
    for (int j = 0; j < 4; j++) acc[i][j] = {0.f, 0.f, 0.f, 0.f};

  for (int k0 = 0; k0 < C_; k0 += 32) {
    *(short8*)&As[r0 * 40 + kc0] = *(const short8*)(a + a0 + k0 + kc0);
    *(short8*)&As[r1 * 40 + kc1] = *(const short8*)(a + a1 + k0 + kc1);
#pragma unroll
    for (int i = 0; i < 4; i++) {
      int r = rbase + 32 * i;
      *(short4v*)&Bs[r * 40 + colf] = f4bf(*(const floatx4*)(w + boff[i] + k0 + colf));
    }
    __syncthreads();
    short8 af[4], bfr[4];
#pragma unroll
    for (int mi = 0; mi < 4; mi++)
      af[mi] = *(const short8*)&As[(wm * 64 + mi * 16 + l15) * 40 + quad * 8];
#pragma unroll
    for (int ni = 0; ni < 4; ni++)
      bfr[ni] = *(const short8*)&Bs[(wn * 64 + ni * 16 + l15) * 40 + quad * 8];
#pragma unroll
    for (int mi = 0; mi < 4; mi++)
#pragma unroll
      for (int ni = 0; ni < 4; ni++)
        acc[mi][ni] = __builtin_amdgcn_mfma_f32_16x16x32_bf16(
            af[mi], bfr[ni], acc[mi][ni], 0, 0, 0);
    __syncthreads();
  }

#pragma unroll
  for (int mi = 0; mi < 4; mi++) {
#pragma unroll
    for (int r = 0; r < 4; r++) {
      int mg = bm * 128 + wm * 64 + mi * 16 + quad * 4 + r;
      size_t rowb = (size_t)mg * C_;
#pragma unroll
      for (int ni = 0; ni < 4; ni++) {
        int jj = bn * 128 + wn * 64 + ni * 16 + l15;
        out[rowb + jj] = acc[mi][ni][r] + bias[jj];
      }
    }
  }
}

extern "C" void kernel_launch(void* const* d_in, const int* in_sizes, int n_in,
                              void* d_out, int out_size, void* d_ws, size_t ws_size,
                              hipStream_t stream) {
  const float* x  = (const float*)d_in[0];
  const float* qw = (const float*)d_in[1];
  const float* pw = (const float*)d_in[2];
  const float* pb = (const float*)d_in[3];
  float* out = (float*)d_out;
  unsigned short* ws  = (unsigned short*)d_ws;
  unsigned short* qkv_buf  = ws;                      // 3 * QKV_PLANE bf16
  unsigned short* attn_buf = ws + 3 * QKV_PLANE;      // 1 * QKV_PLANE bf16

  qkv_gemm<<<dim3(256, 18), dim3(256), 0, stream>>>(x, qw, qkv_buf);
  attn_mfma<<<dim3(1536), dim3(512), 0, stream>>>(qkv_buf, attn_buf);
  proj_gemm<<<dim3(256, 6), dim3(256), 0, stream>>>(attn_buf, pw, pb, out);
}

// Round 4
// 459.140 us; speedup vs baseline: 3.3221x; 1.2650x over previous
//
#include <hip/hip_runtime.h>
#include <hip/hip_bf16.h>

// ===========================================================================
// WindowedAttention: B=8, N=4096, C=768, H=12, HD=64, W=16 -> 16 windows x 256
// I/O float32; internal bf16 MFMA, fp32 accumulate.
//   k0 conv_x/conv_w: f32 -> bf16 pre-pass; x is written WINDOW-PERMUTED so
//                     qkv_gemm A-rows are linear (enables global_load_lds).
//   k1 qkv_gemm_bf  : m97-style (global_load_lds w=16, unpadded 64B LDS rows)
//   k2 attn_mfma    : flash-style per (b,w,h), unchanged from round 3.
//                     Writes attn_buf into the dead xb plane (orig token order)
//   k3 proj_gemm_bf : m97-style, epilogue f32 + bias -> d_out
// ws planes (bf16): [0]=xb->attn_buf, [1]=q, [2]=k, [3]=v, then wb_qkv, wb_proj
// total (4*25165824 + 2304*768 + 768*768)*2 = 206 MB. Fallback to round-3
// convert-in-staging kernels if ws_size is smaller.
// ===========================================================================

using short8  = __attribute__((ext_vector_type(8))) short;
using short4v = __attribute__((ext_vector_type(4))) short;
using floatx4 = __attribute__((ext_vector_type(4))) float;

#define B_    8
#define N_    4096
#define C_    768
#define H_    12
#define HD_   64
#define NW_   256
#define SCALE_ 0.125f
#define QKV_PLANE ((size_t)25165824)   // B*16*12*256*64 == B*N*C

__device__ __forceinline__ float bf2f(unsigned short u) {
  union { unsigned int i; float f; } c; c.i = ((unsigned int)u) << 16; return c.f;
}
__device__ __forceinline__ unsigned short f2bf(float f) {
  unsigned int u = __float_as_uint(f);
  u += 0x7fffu + ((u >> 16) & 1u);   // RNE
  return (unsigned short)(u >> 16);
}
__device__ __forceinline__ short4v f4bf(floatx4 f) {
  short4v s;
  s[0] = (short)f2bf(f[0]); s[1] = (short)f2bf(f[1]);
  s[2] = (short)f2bf(f[2]); s[3] = (short)f2bf(f[3]);
  return s;
}
__device__ __forceinline__ int perm_n(int w, int t) {
  int rb = w >> 2, cb = w & 3, ri = t >> 4, ci = t & 15;
  return ((rb << 4) + ri) * 64 + (cb << 4) + ci;
}
__device__ __forceinline__ void glds16(const unsigned short* g, short* l) {
  __builtin_amdgcn_global_load_lds(
      (const __attribute__((address_space(1))) unsigned int*)g,
      (__attribute__((address_space(3))) unsigned int*)l, 16, 0, 0);
}

// ---------------------------------------------------------------------------
// conv_x: x f32 [b][n][c] -> xb bf16 [b][p][c] with p in window-permuted order
// ---------------------------------------------------------------------------
__global__ __launch_bounds__(192) void conv_x(
    const float* __restrict__ x, unsigned short* __restrict__ xb) {
  int row = blockIdx.x;               // b*4096 + p
  int b = row >> 12, p = row & 4095;
  int n = perm_n(p >> 8, p & 255);
  const float* src = x + ((size_t)(b << 12) + (size_t)n) * C_;
  unsigned short* dst = xb + (size_t)row * C_;
  int c = threadIdx.x << 2;
  *(short4v*)(dst + c) = f4bf(*(const floatx4*)(src + c));
}

// conv_w: qkv_w (2304x768) and proj_w (768x768) f32 -> bf16
__global__ __launch_bounds__(192) void conv_w(
    const float* __restrict__ qw, const float* __restrict__ pw,
    unsigned short* __restrict__ wq, unsigned short* __restrict__ wp) {
  int row = blockIdx.x;
  const float* src; unsigned short* dst;
  if (row < 2304) { src = qw + (size_t)row * C_; dst = wq + (size_t)row * C_; }
  else { src = pw + (size_t)(row - 2304) * C_; dst = wp + (size_t)(row - 2304) * C_; }
  int c = threadIdx.x << 2;
  *(short4v*)(dst + c) = f4bf(*(const floatx4*)(src + c));
}

// ---------------------------------------------------------------------------
// m97-style bf16 GEMM core: 128x128 tile, BK=32, unpadded 64B LDS rows,
// global_load_lds width-16 staging (lane-linear LDS dest). 256 thr = 4 waves.
// ---------------------------------------------------------------------------
#define GEMM_CORE(Aptr, Bptr)                                                  \
  __shared__ short As[128 * 32];                                               \
  __shared__ short Bs[128 * 32];                                               \
  const int tid  = threadIdx.x;                                                \
  const int bm   = blockIdx.x;                                                 \
  const int bn   = blockIdx.y;                                                 \
  const int wave = tid >> 6, lane = tid & 63;                                  \
  const int wm   = wave >> 1, wn = wave & 1;                                   \
  const int l15  = lane & 15, quad = lane >> 4;                                \
  const int srow = tid >> 2, skof = (tid & 3) << 3;                            \
  const unsigned short* ga0 = (Aptr) + (size_t)(bm * 128 + srow) * C_ + skof;  \
  const unsigned short* ga1 = ga0 + (size_t)64 * C_;                           \
  const unsigned short* gb0 = (Bptr) + (size_t)(bn * 128 + srow) * C_ + skof;  \
  const unsigned short* gb1 = gb0 + (size_t)64 * C_;                           \
  short* la0 = As + tid * 8;                                                   \
  short* la1 = As + 2048 + tid * 8;                                            \
  short* lb0 = Bs + tid * 8;                                                   \
  short* lb1 = Bs + 2048 + tid * 8;                                            \
  floatx4 acc[4][4];                                                           \
  _Pragma("unroll") for (int i = 0; i < 4; i++)                                \
      _Pragma("unroll") for (int j = 0; j < 4; j++)                            \
          acc[i][j] = {0.f, 0.f, 0.f, 0.f};                                    \
  for (int k0 = 0; k0 < C_; k0 += 32) {                                        \
    glds16(ga0 + k0, la0);                                                     \
    glds16(ga1 + k0, la1);                                                     \
    glds16(gb0 + k0, lb0);                                                     \
    glds16(gb1 + k0, lb1);                                                     \
    __syncthreads();                                                           \
    short8 af[4], bfr[4];                                                      \
    _Pragma("unroll") for (int mi = 0; mi < 4; mi++)                           \
        af[mi] = *(const short8*)&As[(wm * 64 + mi * 16 + l15) * 32 + quad * 8];\
    _Pragma("unroll") for (int ni = 0; ni < 4; ni++)                           \
        bfr[ni] = *(const short8*)&Bs[(wn * 64 + ni * 16 + l15) * 32 + quad * 8];\
    _Pragma("unroll") for (int mi = 0; mi < 4; mi++)                           \
        _Pragma("unroll") for (int ni = 0; ni < 4; ni++)                       \
            acc[mi][ni] = __builtin_amdgcn_mfma_f32_16x16x32_bf16(             \
                af[mi], bfr[ni], acc[mi][ni], 0, 0, 0);                        \
    __syncthreads();                                                           \
  }

// QKV GEMM: A = xb (permuted, linear), B = wb_qkv. M=32768, N=2304.
__global__ __launch_bounds__(256) void qkv_gemm_bf(
    const unsigned short* __restrict__ a,
    const unsigned short* __restrict__ w,
    unsigned short* __restrict__ qkv) {
  GEMM_CORE(a, w)
  const int which = (bn * 128) / 768;          // 0=q 1=k 2=v
  const int jbase = bn * 128 - which * 768;
  unsigned short* dst = qkv + (size_t)which * QKV_PLANE;
#pragma unroll
  for (int mi = 0; mi < 4; mi++) {
#pragma unroll
    for (int r = 0; r < 4; r++) {
      int mg = bm * 128 + wm * 64 + mi * 16 + quad * 4 + r;
      int b = mg >> 12, p = mg & 4095;
      int wdx = p >> 8, t = p & 255;
      size_t base = (size_t)((b * 16 + wdx) * 12) * (NW_ * HD_) + (size_t)t * HD_;
#pragma unroll
      for (int ni = 0; ni < 4; ni++) {
        int jj = jbase + wn * 64 + ni * 16 + l15;
        int h = jj >> 6, d = jj & 63;
        dst[base + (size_t)h * (NW_ * HD_) + d] = f2bf(acc[mi][ni][r]);
      }
    }
  }
}

// Proj GEMM: A = attn_buf bf16 (linear), B = wb_proj. Out f32 + bias.
__global__ __launch_bounds__(256) void proj_gemm_bf(
    const unsigned short* __restrict__ a,
    const unsigned short* __restrict__ w,
    const float* __restrict__ bias,
    float* __restrict__ out) {
  GEMM_CORE(a, w)
#pragma unroll
  for (int mi = 0; mi < 4; mi++) {
#pragma unroll
    for (int r = 0; r < 4; r++) {
      int mg = bm * 128 + wm * 64 + mi * 16 + quad * 4 + r;
      size_t rowb = (size_t)mg * C_;
#pragma unroll
      for (int ni = 0; ni < 4; ni++) {
        int jj = bn * 128 + wn * 64 + ni * 16 + l15;
        out[rowb + jj] = acc[mi][ni][r] + bias[jj];
      }
    }
  }
}

// ---------------------------------------------------------------------------
// MFMA flash attention (unchanged from round 3).
// ---------------------------------------------------------------------------
__global__ __launch_bounds__(512, 2) void attn_mfma(
    const unsigned short* __restrict__ qkv,
    unsigned short* __restrict__ attn_out) {
  const int bwh = blockIdx.x;
  const int tid = threadIdx.x;
  const int wv = tid >> 6, lane = tid & 63;
  const int l15 = lane & 15, quad = lane >> 4;
  const size_t off = (size_t)bwh * (NW_ * HD_);
  const unsigned short* qb = qkv + off;
  const unsigned short* kb = qkv + QKV_PLANE + off;
  const unsigned short* vb = qkv + 2 * QKV_PLANE + off;

  __shared__ short Ks[64 * 72];
  __shared__ short Vt[64 * 72];
  __shared__ short Ps[8][16 * 72];

  short8 bq[2][2];
#pragma unroll
  for (int c = 0; c < 2; c++) {
    int mc = wv + 8 * c;
#pragma unroll
    for (int kc = 0; kc < 2; kc++)
      bq[c][kc] = *(const short8*)(qb + (mc * 16 + l15) * 64 + kc * 32 + quad * 8);
  }

  floatx4 O[2][4];
#pragma unroll
  for (int c = 0; c < 2; c++)
#pragma unroll
    for (int dt = 0; dt < 4; dt++) O[c][dt] = {0.f, 0.f, 0.f, 0.f};
  float m_run[2] = {-1e30f, -1e30f};
  float l_run[2] = {0.f, 0.f};

  const int sr = tid >> 3;
  const int sc = (tid & 7) << 3;

  for (int t = 0; t < 4; t++) {
    __syncthreads();
    {
      short8 kk8 = *(const short8*)(kb + (t * 64 + sr) * 64 + sc);
      *(short8*)&Ks[sr * 72 + sc] = kk8;
      short8 vv8 = *(const short8*)(vb + (t * 64 + sr) * 64 + sc);
#pragma unroll
      for (int j = 0; j < 8; j++) Vt[(sc + j) * 72 + sr] = vv8[j];
    }
    __syncthreads();

#pragma unroll
    for (int c = 0; c < 2; c++) {
      floatx4 st[4];
#pragma unroll
      for (int nt = 0; nt < 4; nt++) {
        short8 ak0 = *(const short8*)&Ks[(nt * 16 + l15) * 72 + quad * 8];
        short8 ak1 = *(const short8*)&Ks[(nt * 16 + l15) * 72 + 32 + quad * 8];
        floatx4 z = {0.f, 0.f, 0.f, 0.f};
        z = __builtin_amdgcn_mfma_f32_16x16x32_bf16(ak0, bq[c][0], z, 0, 0, 0);
        z = __builtin_amdgcn_mfma_f32_16x16x32_bf16(ak1, bq[c][1], z, 0, 0, 0);
        st[nt] = z;
      }
      float s[16];
      float cmax = -1e30f;
#pragma unroll
      for (int nt = 0; nt < 4; nt++)
#pragma unroll
        for (int r = 0; r < 4; r++) {
          float v = st[nt][r] * SCALE_;
          s[nt * 4 + r] = v;
          cmax = fmaxf(cmax, v);
        }
      cmax = fmaxf(cmax, __shfl_xor(cmax, 16));
      cmax = fmaxf(cmax, __shfl_xor(cmax, 32));
      float nm = fmaxf(m_run[c], cmax);
      float alpha = __expf(m_run[c] - nm);
      m_run[c] = nm;
      float psum = 0.f;
#pragma unroll
      for (int j = 0; j < 16; j++) {
        float p = __expf(s[j] - nm);
        s[j] = p;
        psum += p;
      }
      psum += __shfl_xor(psum, 16);
      psum += __shfl_xor(psum, 32);
      l_run[c] = l_run[c] * alpha + psum;
#pragma unroll
      for (int nt = 0; nt < 4; nt++) {
        short4v pv;
        pv[0] = (short)f2bf(s[nt * 4 + 0]);
        pv[1] = (short)f2bf(s[nt * 4 + 1]);
        pv[2] = (short)f2bf(s[nt * 4 + 2]);
        pv[3] = (short)f2bf(s[nt * 4 + 3]);
        *(short4v*)&Ps[wv][l15 * 72 + nt * 16 + quad * 4] = pv;
      }
      float ar[4];
#pragma unroll
      for (int r = 0; r < 4; r++) ar[r] = __shfl(alpha, quad * 4 + r);
#pragma unroll
      for (int dt = 0; dt < 4; dt++)
#pragma unroll
        for (int r = 0; r < 4; r++) O[c][dt][r] *= ar[r];
#pragma unroll
      for (int kc = 0; kc < 2; kc++) {
        short8 ap = *(const short8*)&Ps[wv][l15 * 72 + kc * 32 + quad * 8];
#pragma unroll
        for (int dt = 0; dt < 4; dt++) {
          short8 bv = *(const short8*)&Vt[(dt * 16 + l15) * 72 + kc * 32 + quad * 8];
          O[c][dt] = __builtin_amdgcn_mfma_f32_16x16x32_bf16(ap, bv, O[c][dt], 0, 0, 0);
        }
      }
    }
  }

  int h = bwh % 12, bw = bwh / 12;
  int b = bw >> 4, wdx = bw & 15;
#pragma unroll
  for (int c = 0; c < 2; c++) {
    float linv = 1.f / l_run[c];
    float lr[4];
#pragma unroll
    for (int r = 0; r < 4; r++) lr[r] = __shfl(linv, quad * 4 + r);
    int mc = wv + 8 * c;
#pragma unroll
    for (int r = 0; r < 4; r++) {
      int q = mc * 16 + quad * 4 + r;
      int n = perm_n(wdx, q);
      unsigned short* op = attn_out + ((size_t)(b * N_ + n)) * C_ + h * HD_;
#pragma unroll
      for (int dt = 0; dt < 4; dt++)
        op[dt * 16 + l15] = f2bf(O[c][dt][r] * lr[r]);
    }
  }
}

// ---------------------------------------------------------------------------
// FALLBACK kernels (round-3 style, used only if ws_size < 206 MB)
// ---------------------------------------------------------------------------
__global__ __launch_bounds__(256) void qkv_gemm_f32(
    const float* __restrict__ x,
    const float* __restrict__ w,
    unsigned short* __restrict__ qkv) {
  __shared__ short As[128 * 40];
  __shared__ short Bs[128 * 40];
  const int tid  = threadIdx.x;
  const int bm   = blockIdx.x;
  const int bn   = blockIdx.y;
  const int wave = tid >> 6, lane = tid & 63;
  const int wm   = wave >> 1, wn = wave & 1;
  const int l15  = lane & 15, quad = lane >> 4;
  const int colf  = (tid & 7) << 2;
  const int rbase = tid >> 3;
  size_t aoff[4], boff[4];
#pragma unroll
  for (int i = 0; i < 4; i++) {
    int r = rbase + 32 * i;
    int mg = bm * 128 + r;
    int b = mg >> 12, p = mg & 4095;
    int n = perm_n(p >> 8, p & 255);
    aoff[i] = ((size_t)(b << 12) + (size_t)n) * C_;
    boff[i] = (size_t)(bn * 128 + r) * C_;
  }
  floatx4 acc[4][4];
#pragma unroll
  for (int i = 0; i < 4; i++)
#pragma unroll
    for (int j = 0; j < 4; j++) acc[i][j] = {0.f, 0.f, 0.f, 0.f};
  for (int k0 = 0; k0 < C_; k0 += 32) {
#pragma unroll
    for (int i = 0; i < 4; i++) {
      int r = rbase + 32 * i;
      *(short4v*)&As[r * 40 + colf] = f4bf(*(const floatx4*)(x + aoff[i] + k0 + colf));
      *(short4v*)&Bs[r * 40 + colf] = f4bf(*(const floatx4*)(w + boff[i] + k0 + colf));
    }
    __syncthreads();
    short8 af[4], bfr[4];
#pragma unroll
    for (int mi = 0; mi < 4; mi++)
      af[mi] = *(const short8*)&As[(wm * 64 + mi * 16 + l15) * 40 + quad * 8];
#pragma unroll
    for (int ni = 0; ni < 4; ni++)
      bfr[ni] = *(const short8*)&Bs[(wn * 64 + ni * 16 + l15) * 40 + quad * 8];
#pragma unroll
    for (int mi = 0; mi < 4; mi++)
#pragma unroll
      for (int ni = 0; ni < 4; ni++)
        acc[mi][ni] = __builtin_amdgcn_mfma_f32_16x16x32_bf16(
            af[mi], bfr[ni], acc[mi][ni], 0, 0, 0);
    __syncthreads();
  }
  const int which = (bn * 128) / 768;
  const int jbase = bn * 128 - which * 768;
  unsigned short* dst = qkv + (size_t)which * QKV_PLANE;
#pragma unroll
  for (int mi = 0; mi < 4; mi++) {
#pragma unroll
    for (int r = 0; r < 4; r++) {
      int mg = bm * 128 + wm * 64 + mi * 16 + quad * 4 + r;
      int b = mg >> 12, p = mg & 4095;
      int wdx = p >> 8, t = p & 255;
      size_t base = (size_t)((b * 16 + wdx) * 12) * (NW_ * HD_) + (size_t)t * HD_;
#pragma unroll
      for (int ni = 0; ni < 4; ni++) {
        int jj = jbase + wn * 64 + ni * 16 + l15;
        int h = jj >> 6, d = jj & 63;
        dst[base + (size_t)h * (NW_ * HD_) + d] = f2bf(acc[mi][ni][r]);
      }
    }
  }
}

__global__ __launch_bounds__(256) void proj_gemm_f32(
    const unsigned short* __restrict__ a,
    const float* __restrict__ w,
    const float* __restrict__ bias,
    float* __restrict__ out) {
  __shared__ short As[128 * 40];
  __shared__ short Bs[128 * 40];
  const int tid  = threadIdx.x;
  const int bm   = blockIdx.x;
  const int bn   = blockIdx.y;
  const int wave = tid >> 6, lane = tid & 63;
  const int wm   = wave >> 1, wn = wave & 1;
  const int l15  = lane & 15, quad = lane >> 4;
  const int c0 = tid, c1 = tid + 256;
  const int r0 = c0 >> 2, kc0 = (c0 & 3) << 3;
  const int r1 = c1 >> 2, kc1 = (c1 & 3) << 3;
  const size_t a0 = (size_t)(bm * 128 + r0) * C_;
  const size_t a1 = (size_t)(bm * 128 + r1) * C_;
  const int colf  = (tid & 7) << 2;
  const int rbase = tid >> 3;
  size_t boff[4];
#pragma unroll
  for (int i = 0; i < 4; i++)
    boff[i] = (size_t)(bn * 128 + rbase + 32 * i) * C_;
  floatx4 acc[4][4];
#pragma unroll
  for (int i = 0; i < 4; i++)
#pragma unroll
    for (int j = 0; j < 4; j++) acc[i][j] = {0.f, 0.f, 0.f, 0.f};
  for (int k0 = 0; k0 < C_; k0 += 32) {
    *(short8*)&As[r0 * 40 + kc0] = *(const short8*)(a + a0 + k0 + kc0);
    *(short8*)&As[r1 * 40 + kc1] = *(const short8*)(a + a1 + k0 + kc1);
#pragma unroll
    for (int i = 0; i < 4; i++) {
      int r = rbase + 32 * i;
      *(short4v*)&Bs[r * 40 + colf] = f4bf(*(const floatx4*)(w + boff[i] + k0 + colf));
    }
    __syncthreads();
    short8 af[4], bfr[4];
#pragma unroll
    for (int mi = 0; mi < 4; mi++)
      af[mi] = *(const short8*)&As[(wm * 64 + mi * 16 + l15) * 40 + quad * 8];
#pragma unroll
    for (int ni = 0; ni < 4; ni++)
      bfr[ni] = *(const short8*)&Bs[(wn * 64 + ni * 16 + l15) * 40 + quad * 8];
#pragma unroll
    for (int mi = 0; mi < 4; mi++)
#pragma unroll
      for (int ni = 0; ni < 4; ni++)
        acc[mi][ni] = __builtin_amdgcn_mfma_f32_16x16x32_bf16(
            af[mi], bfr[ni], acc[mi][ni], 0, 0, 0);
    __syncthreads();
  }
#pragma unroll
  for (int mi = 0; mi < 4; mi++) {
#pragma unroll
    for (int r = 0; r < 4; r++) {
      int mg = bm * 128 + wm * 64 + mi * 16 + quad * 4 + r;
      size_t rowb = (size_t)mg * C_;
#pragma unroll
      for (int ni = 0; ni < 4; ni++) {
        int jj = bn * 128 + wn * 64 + ni * 16 + l15;
        out[rowb + jj] = acc[mi][ni][r] + bias[jj];
      }
    }
  }
}

extern "C" void kernel_launch(void* const* d_in, const int* in_sizes, int n_in,
                              void* d_out, int out_size, void* d_ws, size_t ws_size,
                              hipStream_t stream) {
  const float* x  = (const float*)d_in[0];
  const float* qw = (const float*)d_in[1];
  const float* pw = (const float*)d_in[2];
  const float* pb = (const float*)d_in[3];
  float* out = (float*)d_out;
  unsigned short* ws = (unsigned short*)d_ws;

  unsigned short* xb       = ws;                    // plane 0 (xb, then attn_buf)
  unsigned short* qkv_buf  = ws + QKV_PLANE;        // planes 1..3 = q,k,v
  unsigned short* attn_buf = ws;                    // reuses plane 0
  unsigned short* wb_qkv   = ws + 4 * QKV_PLANE;                  // 2304*768
  unsigned short* wb_proj  = wb_qkv + (size_t)2304 * 768;         // 768*768

  const size_t need = (4 * QKV_PLANE + (size_t)2304 * 768 + (size_t)768 * 768) * 2;
  if (ws_size >= need) {
    conv_x<<<dim3(B_ * N_), dim3(192), 0, stream>>>(x, xb);
    conv_w<<<dim3(3072), dim3(192), 0, stream>>>(qw, pw, wb_qkv, wb_proj);
    qkv_gemm_bf<<<dim3(256, 18), dim3(256), 0, stream>>>(xb, wb_qkv, qkv_buf);
    attn_mfma<<<dim3(1536), dim3(512), 0, stream>>>(qkv_buf, attn_buf);
    proj_gemm_bf<<<dim3(256, 6), dim3(256), 0, stream>>>(attn_buf, wb_proj, pb, out);
  } else {
    qkv_gemm_f32<<<dim3(256, 18), dim3(256), 0, stream>>>(x, qw, qkv_buf);
    attn_mfma<<<dim3(1536), dim3(512), 0, stream>>>(qkv_buf, attn_buf);
    proj_gemm_f32<<<dim3(256, 6), dim3(256), 0, stream>>>(attn_buf, pw, pb, out);
  }
}